// Round 4
// baseline (201.387 us; speedup 1.0000x reference)
//
#include <hip/hip_runtime.h>
#include <hip/hip_bf16.h>
#include <math.h>

#define NN 100000
#define DD 384
#define HH 128
#define KK 5

typedef __attribute__((ext_vector_type(8))) short short8;
typedef __attribute__((ext_vector_type(4))) float f32x4;

constexpr float INIT_VAL = 1.4142135623730951e-3f; // 1/sqrt(N*K)
constexpr float RSQRT5   = 0.44721359549995793f;   // 1/sqrt(5)

// split f32 -> bf16 hi + bf16 lo (truncation; |x - hi - lo| <= 2^-16 |x|)
__device__ __forceinline__ void split_bf16(float x, ushort& hi, ushort& lo) {
    unsigned xb = __float_as_uint(x);
    hi = (ushort)(xb >> 16);
    float hif = __uint_as_float(((unsigned)hi) << 16);
    lo = (ushort)(__float_as_uint(x - hif) >> 16);
}

// split 8 floats (two float4, k-consecutive) into hi/lo bf16 short8 fragments
__device__ __forceinline__ void split8(float4 x, float4 y, short8& h, short8& l) {
    union { short8 s; unsigned u[4]; } H, L;
    float f[8] = {x.x, x.y, x.z, x.w, y.x, y.y, y.z, y.w};
#pragma unroll
    for (int d = 0; d < 4; ++d) {
        unsigned b0 = __float_as_uint(f[2 * d]);
        unsigned b1 = __float_as_uint(f[2 * d + 1]);
        H.u[d] = (b0 >> 16) | (b1 & 0xFFFF0000u);
        float l0 = f[2 * d]     - __uint_as_float(b0 & 0xFFFF0000u);
        float l1 = f[2 * d + 1] - __uint_as_float(b1 & 0xFFFF0000u);
        L.u[d] = (__float_as_uint(l0) >> 16) | (__float_as_uint(l1) & 0xFFFF0000u);
    }
    h = H.s;
    l = L.s;
}

// ---------------- fused prep ----------------
__global__ __launch_bounds__(256) void prep_kernel(
    const float* __restrict__ qv, const float* __restrict__ W1,
    const float* __restrict__ b1, const int* __restrict__ nbr,
    float* __restrict__ b1p, ushort* __restrict__ W1h, ushort* __restrict__ W1l,
    int* __restrict__ nbrT, float* __restrict__ sA, float* __restrict__ sB,
    float* __restrict__ sC, float* __restrict__ ssp) {
    const int b = blockIdx.x, tid = threadIdx.x;
    if (b == 0) {
        if (tid == 0) ssp[0] = 0.f;
        if (tid < HH) {
            float s = b1[tid];
#pragma unroll 16
            for (int k = 0; k < DD; ++k)
                s = fmaf(qv[k], W1[(size_t)(DD + k) * HH + tid], s);
            b1p[tid] = s;
        }
    } else if (b <= 24) {
        int t = (b - 1) * 256 + tid;       // t = (c*12 + ks)*64 + lane, t < 6144
        int l = t & 63;
        int ks = (t >> 6) % 12;
        int c = (t >> 6) / 12;
        int k0 = ks * 32 + ((l >> 4) << 3);
        int col = c * 16 + (l & 15);
#pragma unroll
        for (int e = 0; e < 8; ++e) {
            ushort hv, lv;
            split_bf16(W1[(size_t)(k0 + e) * HH + col], hv, lv);
            W1h[(size_t)t * 8 + e] = hv;
            W1l[(size_t)t * 8 + e] = lv;
        }
    } else {
        int i = (b - 25) * 256 + tid;
        if (i < NN) {
#pragma unroll
            for (int j = 0; j < KK; ++j) {
                nbrT[j * NN + i] = nbr[i * KK + j];
                sA[j * NN + i] = 0.f;
                sB[j * NN + i] = 0.f;
                sC[j * NN + i] = 0.f;
            }
        }
    }
}

// ---------------- wave-independent MFMA MLP ----------------
// 256 thr = 4 waves; wave w: nodes blockIdx*64 + (w>>1)*32 .. +32, hidden half wn = w&1.
// A read directly from global (f32, split in-reg), B pre-packed fragments from L2.
// No main-loop LDS/barriers; one barrier for the tiny epilogue reduce buffer.
__global__ __launch_bounds__(256, 4) void mlp_mfma_kernel(
    const float* __restrict__ emb, const ushort* __restrict__ W1h,
    const ushort* __restrict__ W1l, const float* __restrict__ b1p,
    const float* __restrict__ W2, const float* __restrict__ b2,
    float* __restrict__ gout /* [KK][NN] */) {
    __shared__ float pbuf[64][2][8];   // 4 KB

    const int tid = threadIdx.x;
    const int lane = tid & 63;
    const int wid = tid >> 6;
    const int wm = wid >> 1;   // node half within block
    const int wn = wid & 1;    // hidden half
    const int blkBase = blockIdx.x * 64;
    const int waveBase = blkBase + wm * 32;

    // per-lane A row pointers (clamped; OOB rows masked at the epilogue)
    int r0 = waveBase + (lane & 15);
    int r1 = r0 + 16;
    r0 = min(r0, NN - 1);
    r1 = min(r1, NN - 1);
    const float* p0 = emb + (size_t)r0 * DD + ((lane >> 4) << 3);
    const float* p1 = emb + (size_t)r1 * DD + ((lane >> 4) << 3);

    f32x4 acc[2][4];
#pragma unroll
    for (int mt = 0; mt < 2; ++mt)
#pragma unroll
        for (int nt = 0; nt < 4; ++nt) acc[mt][nt] = (f32x4){0.f, 0.f, 0.f, 0.f};

    // rotating raw-A registers (one ks ahead)
    float4 a0A = *reinterpret_cast<const float4*>(p0);
    float4 a0B = *reinterpret_cast<const float4*>(p0 + 4);
    float4 a1A = *reinterpret_cast<const float4*>(p1);
    float4 a1B = *reinterpret_cast<const float4*>(p1 + 4);

#pragma unroll 2
    for (int ks = 0; ks < 12; ++ks) {
        float4 n0A, n0B, n1A, n1B;
        if (ks < 11) {
            const float* q0 = p0 + (ks + 1) * 32;
            const float* q1 = p1 + (ks + 1) * 32;
            n0A = *reinterpret_cast<const float4*>(q0);
            n0B = *reinterpret_cast<const float4*>(q0 + 4);
            n1A = *reinterpret_cast<const float4*>(q1);
            n1B = *reinterpret_cast<const float4*>(q1 + 4);
        }
        // B fragments for this ks
        short8 bh[4], bl[4];
#pragma unroll
        for (int nt = 0; nt < 4; ++nt) {
            size_t off = ((size_t)((wn * 4 + nt) * 12 + ks) * 64 + lane) * 8;
            bh[nt] = *reinterpret_cast<const short8*>(&W1h[off]);
            bl[nt] = *reinterpret_cast<const short8*>(&W1l[off]);
        }
        // split current raw A
        short8 ah[2], al[2];
        split8(a0A, a0B, ah[0], al[0]);
        split8(a1A, a1B, ah[1], al[1]);
        // MFMA: hh first, then lh, then hl (gives bl loads extra slack)
#pragma unroll
        for (int nt = 0; nt < 4; ++nt) {
            acc[0][nt] = __builtin_amdgcn_mfma_f32_16x16x32_bf16(ah[0], bh[nt], acc[0][nt], 0, 0, 0);
            acc[1][nt] = __builtin_amdgcn_mfma_f32_16x16x32_bf16(ah[1], bh[nt], acc[1][nt], 0, 0, 0);
        }
#pragma unroll
        for (int nt = 0; nt < 4; ++nt) {
            acc[0][nt] = __builtin_amdgcn_mfma_f32_16x16x32_bf16(al[0], bh[nt], acc[0][nt], 0, 0, 0);
            acc[1][nt] = __builtin_amdgcn_mfma_f32_16x16x32_bf16(al[1], bh[nt], acc[1][nt], 0, 0, 0);
        }
#pragma unroll
        for (int nt = 0; nt < 4; ++nt) {
            acc[0][nt] = __builtin_amdgcn_mfma_f32_16x16x32_bf16(ah[0], bl[nt], acc[0][nt], 0, 0, 0);
            acc[1][nt] = __builtin_amdgcn_mfma_f32_16x16x32_bf16(ah[1], bl[nt], acc[1][nt], 0, 0, 0);
        }
        a0A = n0A; a0B = n0B; a1A = n1A; a1B = n1B;
    }

    // epilogue: v = relu(h + b1p); p[j] = sum_h v * W2[h][j]; reduce over 16 lanes
    float b1v[4], w2v[4][KK];
#pragma unroll
    for (int nt = 0; nt < 4; ++nt) {
        int h = wn * 64 + nt * 16 + (lane & 15);
        b1v[nt] = b1p[h];
#pragma unroll
        for (int j = 0; j < KK; ++j) w2v[nt][j] = W2[h * KK + j];
    }
#pragma unroll
    for (int mt = 0; mt < 2; ++mt) {
        float p[4][KK];
#pragma unroll
        for (int r = 0; r < 4; ++r)
#pragma unroll
            for (int j = 0; j < KK; ++j) p[r][j] = 0.f;
#pragma unroll
        for (int nt = 0; nt < 4; ++nt)
#pragma unroll
            for (int r = 0; r < 4; ++r) {
                float v = fmaxf(acc[mt][nt][r] + b1v[nt], 0.f);
#pragma unroll
                for (int j = 0; j < KK; ++j) p[r][j] = fmaf(v, w2v[nt][j], p[r][j]);
            }
#pragma unroll
        for (int off = 1; off < 16; off <<= 1)
#pragma unroll
            for (int r = 0; r < 4; ++r)
#pragma unroll
                for (int j = 0; j < KK; ++j) p[r][j] += __shfl_xor(p[r][j], off, 64);
        if ((lane & 15) == 0) {
            int rowbase = wm * 32 + mt * 16 + (lane >> 4) * 4;
#pragma unroll
            for (int r = 0; r < 4; ++r)
#pragma unroll
                for (int j = 0; j < KK; ++j) pbuf[rowbase + r][wn][j] = p[r][j];
        }
    }
    __syncthreads();
    if (tid < 64) {
        int node = blkBase + tid;
        float a[KK], an2 = 0.f;
#pragma unroll
        for (int j = 0; j < KK; ++j) {
            a[j] = pbuf[tid][0][j] + pbuf[tid][1][j] + b2[j];
            an2 = fmaf(a[j], a[j], an2);
        }
        float an = sqrtf(an2);
        bool valid = (an2 > 0.f) && isfinite(an);
        if (node < NN) {
#pragma unroll
            for (int j = 0; j < KK; ++j)
                gout[j * NN + node] = valid ? (a[j] / an) : RSQRT5;
        }
    }
}

// ---------------- walk step 1: state is uniform INIT_VAL, no read ----------------
__global__ void walk_step_first(const float* __restrict__ g, const int* __restrict__ nbrT,
                                float* __restrict__ v) {
    int i = blockIdx.x * blockDim.x + threadIdx.x;
    if (i >= NN) return;
    float gj[KK], s = 0.f;
#pragma unroll
    for (int j = 0; j < KK; ++j) {
        gj[j] = g[j * NN + i];
        s += gj[j];
    }
    float d = s * INIT_VAL;
#pragma unroll
    for (int j = 0; j < KK; ++j)
        atomicAdd(&v[j * NN + nbrT[j * NN + i]], gj[j] * d);
}

// ---------------- walk step: s_p = g (g.u); scatter-add ----------------
__global__ void walk_step_kernel(const float* __restrict__ g, const int* __restrict__ nbrT,
                                 const float* __restrict__ u, float* __restrict__ v) {
    int i = blockIdx.x * blockDim.x + threadIdx.x;
    if (i >= NN) return;
    float gj[KK], d = 0.f;
#pragma unroll
    for (int j = 0; j < KK; ++j) {
        gj[j] = g[j * NN + i];
        d = fmaf(gj[j], u[j * NN + i], d);
    }
#pragma unroll
    for (int j = 0; j < KK; ++j)
        atomicAdd(&v[j * NN + nbrT[j * NN + i]], gj[j] * d);
}

// ---------------- global sum of squares (float4) ----------------
__global__ void norm_reduce_kernel(const float* __restrict__ u, float* __restrict__ ss) {
    int i = blockIdx.x * blockDim.x + threadIdx.x;
    const int total4 = (KK * NN) / 4;  // 125000
    float s = 0.f;
    for (int idx = i; idx < total4; idx += gridDim.x * blockDim.x) {
        float4 x = reinterpret_cast<const float4*>(u)[idx];
        s = fmaf(x.x, x.x, s);
        s = fmaf(x.y, x.y, s);
        s = fmaf(x.z, x.z, s);
        s = fmaf(x.w, x.w, s);
    }
#pragma unroll
    for (int off = 32; off > 0; off >>= 1) s += __shfl_xor(s, off, 64);
    if ((threadIdx.x & 63) == 0) atomicAdd(ss, s);
}

// ---------------- out[i] = sum_j |u[j][i]| / ||u|| ----------------
__global__ void finalize_kernel(const float* __restrict__ u, const float* __restrict__ ss,
                                float* __restrict__ out) {
    int i = blockIdx.x * blockDim.x + threadIdx.x;
    if (i >= NN) return;
    float s = 0.f;
#pragma unroll
    for (int j = 0; j < KK; ++j) s += fabsf(u[j * NN + i]);
    float nrm = sqrtf(*ss);
    out[i] = (nrm > 0.f) ? (s / nrm) : (KK * INIT_VAL);
}

extern "C" void kernel_launch(void* const* d_in, const int* in_sizes, int n_in,
                              void* d_out, int out_size, void* d_ws, size_t ws_size,
                              hipStream_t stream) {
    const float* emb = (const float*)d_in[0];
    const float* qv  = (const float*)d_in[1];
    const float* W1  = (const float*)d_in[2];
    const float* b1  = (const float*)d_in[3];
    const float* W2  = (const float*)d_in[4];
    const float* b2  = (const float*)d_in[5];
    const int*   nbr = (const int*)d_in[6];
    float* out = (float*)d_out;

    char* ws = (char*)d_ws;
    size_t off = 0;
    auto alloc = [&](size_t bytes) {
        char* p = ws + off;
        off += (bytes + 255) & ~(size_t)255;
        return p;
    };
    float*  b1p  = (float*)alloc(HH * sizeof(float));
    ushort* W1h  = (ushort*)alloc((size_t)DD * HH * sizeof(ushort));
    ushort* W1l  = (ushort*)alloc((size_t)DD * HH * sizeof(ushort));
    float*  gbuf = (float*)alloc((size_t)KK * NN * sizeof(float));
    int*    nbrT = (int*)  alloc((size_t)KK * NN * sizeof(int));
    float*  sA   = (float*)alloc((size_t)KK * NN * sizeof(float));
    float*  sB   = (float*)alloc((size_t)KK * NN * sizeof(float));
    float*  sC   = (float*)alloc((size_t)KK * NN * sizeof(float));
    float*  ssp  = (float*)alloc(sizeof(float));

    const int nblk = (NN + 255) / 256;

    prep_kernel<<<25 + nblk, 256, 0, stream>>>(qv, W1, b1, nbr, b1p, W1h, W1l,
                                               nbrT, sA, sB, sC, ssp);
    mlp_mfma_kernel<<<(NN + 63) / 64, 256, 0, stream>>>(emb, W1h, W1l, b1p, W2, b2, gbuf);

    walk_step_first<<<nblk, 256, 0, stream>>>(gbuf, nbrT, sA);
    walk_step_kernel<<<nblk, 256, 0, stream>>>(gbuf, nbrT, sA, sB);
    walk_step_kernel<<<nblk, 256, 0, stream>>>(gbuf, nbrT, sB, sC);

    norm_reduce_kernel<<<512, 256, 0, stream>>>(sC, ssp);
    finalize_kernel<<<nblk, 256, 0, stream>>>(sC, ssp, out);
}

// Round 5
// 173.423 us; speedup vs baseline: 1.1612x; 1.1612x over previous
//
#include <hip/hip_runtime.h>
#include <hip/hip_bf16.h>
#include <math.h>

#define NN 100000
#define DD 384
#define HH 128
#define KK 5

typedef __attribute__((ext_vector_type(8))) short short8;
typedef __attribute__((ext_vector_type(4))) float f32x4;

constexpr float INIT_VAL = 1.4142135623730951e-3f; // 1/sqrt(N*K)
constexpr float RSQRT5   = 0.44721359549995793f;   // 1/sqrt(5)

// split f32 -> bf16 hi + bf16 lo (truncation; |x - hi - lo| <= 2^-16 |x|)
__device__ __forceinline__ void split_bf16(float x, ushort& hi, ushort& lo) {
    unsigned xb = __float_as_uint(x);
    hi = (ushort)(xb >> 16);
    float hif = __uint_as_float(((unsigned)hi) << 16);
    lo = (ushort)(__float_as_uint(x - hif) >> 16);
}

// split 8 floats (two float4, k-consecutive) into hi/lo bf16 short8 fragments
__device__ __forceinline__ void split8(float4 x, float4 y, short8& h, short8& l) {
    union { short8 s; unsigned u[4]; } H, L;
    float f[8] = {x.x, x.y, x.z, x.w, y.x, y.y, y.z, y.w};
#pragma unroll
    for (int d = 0; d < 4; ++d) {
        unsigned b0 = __float_as_uint(f[2 * d]);
        unsigned b1 = __float_as_uint(f[2 * d + 1]);
        H.u[d] = (b0 >> 16) | (b1 & 0xFFFF0000u);
        float l0 = f[2 * d]     - __uint_as_float(b0 & 0xFFFF0000u);
        float l1 = f[2 * d + 1] - __uint_as_float(b1 & 0xFFFF0000u);
        L.u[d] = (__float_as_uint(l0) >> 16) | (__float_as_uint(l1) & 0xFFFF0000u);
    }
    h = H.s;
    l = L.s;
}

// async global -> LDS, 16 bytes per lane; lds base must be wave-uniform
typedef __attribute__((address_space(3))) unsigned lds_as_t;
typedef __attribute__((address_space(1))) const unsigned glb_as_t;
__device__ __forceinline__ void gload_lds16(const float* g, float* l) {
    __builtin_amdgcn_global_load_lds((glb_as_t*)g, (lds_as_t*)l, 16, 0, 0);
}

// ---------------- fused prep ----------------
__global__ __launch_bounds__(256) void prep_kernel(
    const float* __restrict__ qv, const float* __restrict__ W1,
    const float* __restrict__ b1, const int* __restrict__ nbr,
    float* __restrict__ b1p, ushort* __restrict__ W1h, ushort* __restrict__ W1l,
    int* __restrict__ nbrT, float* __restrict__ sA, float* __restrict__ sB,
    float* __restrict__ sC, float* __restrict__ ssp) {
    const int b = blockIdx.x, tid = threadIdx.x;
    if (b == 0) {
        if (tid == 0) ssp[0] = 0.f;
        if (tid < HH) {
            float s = b1[tid];
#pragma unroll 16
            for (int k = 0; k < DD; ++k)
                s = fmaf(qv[k], W1[(size_t)(DD + k) * HH + tid], s);
            b1p[tid] = s;
        }
    } else if (b <= 24) {
        int t = (b - 1) * 256 + tid;       // t = (c*12 + ks)*64 + lane, t < 6144
        int l = t & 63;
        int ks = (t >> 6) % 12;
        int c = (t >> 6) / 12;
        int k0 = ks * 32 + ((l >> 4) << 3);
        int col = c * 16 + (l & 15);
#pragma unroll
        for (int e = 0; e < 8; ++e) {
            ushort hv, lv;
            split_bf16(W1[(size_t)(k0 + e) * HH + col], hv, lv);
            W1h[(size_t)t * 8 + e] = hv;
            W1l[(size_t)t * 8 + e] = lv;
        }
    } else {
        int i = (b - 25) * 256 + tid;
        if (i < NN) {
#pragma unroll
            for (int j = 0; j < KK; ++j) {
                nbrT[j * NN + i] = nbr[i * KK + j];
                sA[j * NN + i] = 0.f;
                sB[j * NN + i] = 0.f;
                sC[j * NN + i] = 0.f;
            }
        }
    }
}

// ---------------- MFMA MLP: 2-phase gload_lds pipeline ----------------
// 256 thr = 4 waves (2 M-halves x 2 hidden-halves); tile 64 nodes x 128 hidden.
// A tile (f32, 64x128k) double-buffered in LDS via global_load_lds width 16.
// LDS layout: row-major 512B rows; 16B chunk b of row r holds source chunk
// b ^ ((r&31)<<4) (swizzled at the GLOBAL SOURCE, linear LDS dest, swizzled read).
// Epilogue fuses walk step 1 (state uniform -> scatter g_j * INIT*sum(g)).
__global__ __launch_bounds__(256, 2) void mlp_mfma_kernel(
    const float* __restrict__ emb, const ushort* __restrict__ W1h,
    const ushort* __restrict__ W1l, const float* __restrict__ b1p,
    const float* __restrict__ W2, const float* __restrict__ b2,
    const int* __restrict__ nbrT, float* __restrict__ gout /* [KK][NN] */,
    float* __restrict__ sA) {
    __shared__ __align__(16) float Abuf[2][64][128];  // 64 KB
    __shared__ float pbuf[64][2][8];                  // 4 KB

    const int tid = threadIdx.x;
    const int lane = tid & 63;
    const int wid = tid >> 6;
    const int wm = wid >> 1;   // M half (32 rows)
    const int wn = wid & 1;    // hidden half (64 cols)
    const int blkBase = blockIdx.x * 64;

    const int lrow = lane >> 5;     // 0/1: which of the 2 rows this instr stages
    const int lc16 = lane & 31;     // 16B chunk within the 512B row

    // stage tile t (k window t*128..+128) into Abuf[buf]; 8 instrs/wave, 1KB each
    auto stage = [&](int buf, int t) {
        const int kbase = t * 128;
#pragma unroll
        for (int s = 0; s < 8; ++s) {
            int rl = wid * 16 + s * 2;          // wave-uniform row base
            int r = rl + lrow;                  // per-lane row (0..63)
            int node = min(blkBase + r, NN - 1);
            int sb = (lc16 * 16) ^ ((r & 31) << 4);  // swizzled source byte
            gload_lds16(emb + (size_t)node * DD + kbase + (sb >> 2), &Abuf[buf][rl][0]);
        }
    };

    f32x4 acc[2][4];
#pragma unroll
    for (int mt = 0; mt < 2; ++mt)
#pragma unroll
        for (int nt = 0; nt < 4; ++nt) acc[mt][nt] = (f32x4){0.f, 0.f, 0.f, 0.f};

    stage(0, 0);
    __syncthreads();   // drains vmcnt -> buf0 ready

#pragma unroll
    for (int t = 0; t < 3; ++t) {
        if (t < 2) stage((t + 1) & 1, t + 1);   // in flight across compute phase
        const int buf = t & 1;

        short8 bh[2][4], bl[2][4];
        auto loadB = [&](int kt, int sb2) {
            int ks = t * 4 + kt;
#pragma unroll
            for (int nt = 0; nt < 4; ++nt) {
                size_t off = ((size_t)((wn * 4 + nt) * 12 + ks) * 64 + lane) * 8;
                bh[sb2][nt] = *reinterpret_cast<const short8*>(&W1h[off]);
                bl[sb2][nt] = *reinterpret_cast<const short8*>(&W1l[off]);
            }
        };
        loadB(0, 0);
#pragma unroll
        for (int kt = 0; kt < 4; ++kt) {
            const int cur = kt & 1, nxt = cur ^ 1;
            if (kt < 3) loadB(kt + 1, nxt);
            // A fragments: swizzled f32 reads, split to bf16 hi/lo in-reg
            short8 ah[2], al[2];
#pragma unroll
            for (int mt = 0; mt < 2; ++mt) {
                int row = wm * 32 + mt * 16 + (lane & 15);
                int c0 = kt * 128 + ((lane >> 4) << 5);
                int sw = (row & 31) << 4;
                const char* base = (const char*)(&Abuf[buf][row][0]);
                float4 x = *(const float4*)(base + (c0 ^ sw));
                float4 y = *(const float4*)(base + ((c0 + 16) ^ sw));
                split8(x, y, ah[mt], al[mt]);
            }
#pragma unroll
            for (int nt = 0; nt < 4; ++nt) {
                acc[0][nt] = __builtin_amdgcn_mfma_f32_16x16x32_bf16(ah[0], bh[cur][nt], acc[0][nt], 0, 0, 0);
                acc[1][nt] = __builtin_amdgcn_mfma_f32_16x16x32_bf16(ah[1], bh[cur][nt], acc[1][nt], 0, 0, 0);
            }
#pragma unroll
            for (int nt = 0; nt < 4; ++nt) {
                acc[0][nt] = __builtin_amdgcn_mfma_f32_16x16x32_bf16(al[0], bh[cur][nt], acc[0][nt], 0, 0, 0);
                acc[1][nt] = __builtin_amdgcn_mfma_f32_16x16x32_bf16(al[1], bh[cur][nt], acc[1][nt], 0, 0, 0);
            }
#pragma unroll
            for (int nt = 0; nt < 4; ++nt) {
                acc[0][nt] = __builtin_amdgcn_mfma_f32_16x16x32_bf16(ah[0], bl[cur][nt], acc[0][nt], 0, 0, 0);
                acc[1][nt] = __builtin_amdgcn_mfma_f32_16x16x32_bf16(ah[1], bl[cur][nt], acc[1][nt], 0, 0, 0);
            }
        }
        __syncthreads();  // drains stage(t+1); also releases buf for t+2
    }

    // epilogue: v = relu(h + b1p); p[j] = sum_h v * W2[h][j]; reduce over 16 lanes
    float b1v[4], w2v[4][KK];
#pragma unroll
    for (int nt = 0; nt < 4; ++nt) {
        int h = wn * 64 + nt * 16 + (lane & 15);
        b1v[nt] = b1p[h];
#pragma unroll
        for (int j = 0; j < KK; ++j) w2v[nt][j] = W2[h * KK + j];
    }
#pragma unroll
    for (int mt = 0; mt < 2; ++mt) {
        float p[4][KK];
#pragma unroll
        for (int r = 0; r < 4; ++r)
#pragma unroll
            for (int j = 0; j < KK; ++j) p[r][j] = 0.f;
#pragma unroll
        for (int nt = 0; nt < 4; ++nt)
#pragma unroll
            for (int r = 0; r < 4; ++r) {
                float v = fmaxf(acc[mt][nt][r] + b1v[nt], 0.f);
#pragma unroll
                for (int j = 0; j < KK; ++j) p[r][j] = fmaf(v, w2v[nt][j], p[r][j]);
            }
#pragma unroll
        for (int off = 1; off < 16; off <<= 1)
#pragma unroll
            for (int r = 0; r < 4; ++r)
#pragma unroll
                for (int j = 0; j < KK; ++j) p[r][j] += __shfl_xor(p[r][j], off, 64);
        if ((lane & 15) == 0) {
            int rowbase = wm * 32 + mt * 16 + (lane >> 4) * 4;
#pragma unroll
            for (int r = 0; r < 4; ++r)
#pragma unroll
                for (int j = 0; j < KK; ++j) pbuf[rowbase + r][wn][j] = p[r][j];
        }
    }
    __syncthreads();
    if (tid < 64) {
        int node = blkBase + tid;
        float a[KK], an2 = 0.f;
#pragma unroll
        for (int j = 0; j < KK; ++j) {
            a[j] = pbuf[tid][0][j] + pbuf[tid][1][j] + b2[j];
            an2 = fmaf(a[j], a[j], an2);
        }
        float an = sqrtf(an2);
        bool valid = (an2 > 0.f) && isfinite(an);
        if (node < NN) {
            float g5[KK], ssum = 0.f;
#pragma unroll
            for (int j = 0; j < KK; ++j) {
                g5[j] = valid ? (a[j] / an) : RSQRT5;
                gout[j * NN + node] = g5[j];
                ssum += g5[j];
            }
            // fused walk step 1: state uniform INIT_VAL -> d = INIT * sum(g)
            float d = ssum * INIT_VAL;
#pragma unroll
            for (int j = 0; j < KK; ++j)
                atomicAdd(&sA[j * NN + nbrT[j * NN + node]], g5[j] * d);
        }
    }
}

// ---------------- walk step: s_p = g (g.u); scatter-add ----------------
__global__ void walk_step_kernel(const float* __restrict__ g, const int* __restrict__ nbrT,
                                 const float* __restrict__ u, float* __restrict__ v) {
    int i = blockIdx.x * blockDim.x + threadIdx.x;
    if (i >= NN) return;
    float gj[KK], d = 0.f;
#pragma unroll
    for (int j = 0; j < KK; ++j) {
        gj[j] = g[j * NN + i];
        d = fmaf(gj[j], u[j * NN + i], d);
    }
#pragma unroll
    for (int j = 0; j < KK; ++j)
        atomicAdd(&v[j * NN + nbrT[j * NN + i]], gj[j] * d);
}

// ---------------- global sum of squares (float4) ----------------
__global__ void norm_reduce_kernel(const float* __restrict__ u, float* __restrict__ ss) {
    int i = blockIdx.x * blockDim.x + threadIdx.x;
    const int total4 = (KK * NN) / 4;  // 125000
    float s = 0.f;
    for (int idx = i; idx < total4; idx += gridDim.x * blockDim.x) {
        float4 x = reinterpret_cast<const float4*>(u)[idx];
        s = fmaf(x.x, x.x, s);
        s = fmaf(x.y, x.y, s);
        s = fmaf(x.z, x.z, s);
        s = fmaf(x.w, x.w, s);
    }
#pragma unroll
    for (int off = 32; off > 0; off >>= 1) s += __shfl_xor(s, off, 64);
    if ((threadIdx.x & 63) == 0) atomicAdd(ss, s);
}

// ---------------- out[i] = sum_j |u[j][i]| / ||u|| ----------------
__global__ void finalize_kernel(const float* __restrict__ u, const float* __restrict__ ss,
                                float* __restrict__ out) {
    int i = blockIdx.x * blockDim.x + threadIdx.x;
    if (i >= NN) return;
    float s = 0.f;
#pragma unroll
    for (int j = 0; j < KK; ++j) s += fabsf(u[j * NN + i]);
    float nrm = sqrtf(*ss);
    out[i] = (nrm > 0.f) ? (s / nrm) : (KK * INIT_VAL);
}

extern "C" void kernel_launch(void* const* d_in, const int* in_sizes, int n_in,
                              void* d_out, int out_size, void* d_ws, size_t ws_size,
                              hipStream_t stream) {
    const float* emb = (const float*)d_in[0];
    const float* qv  = (const float*)d_in[1];
    const float* W1  = (const float*)d_in[2];
    const float* b1  = (const float*)d_in[3];
    const float* W2  = (const float*)d_in[4];
    const float* b2  = (const float*)d_in[5];
    const int*   nbr = (const int*)d_in[6];
    float* out = (float*)d_out;

    char* ws = (char*)d_ws;
    size_t off = 0;
    auto alloc = [&](size_t bytes) {
        char* p = ws + off;
        off += (bytes + 255) & ~(size_t)255;
        return p;
    };
    float*  b1p  = (float*)alloc(HH * sizeof(float));
    ushort* W1h  = (ushort*)alloc((size_t)DD * HH * sizeof(ushort));
    ushort* W1l  = (ushort*)alloc((size_t)DD * HH * sizeof(ushort));
    float*  gbuf = (float*)alloc((size_t)KK * NN * sizeof(float));
    int*    nbrT = (int*)  alloc((size_t)KK * NN * sizeof(int));
    float*  sA   = (float*)alloc((size_t)KK * NN * sizeof(float));
    float*  sB   = (float*)alloc((size_t)KK * NN * sizeof(float));
    float*  sC   = (float*)alloc((size_t)KK * NN * sizeof(float));
    float*  ssp  = (float*)alloc(sizeof(float));

    const int nblk = (NN + 255) / 256;

    prep_kernel<<<25 + nblk, 256, 0, stream>>>(qv, W1, b1, nbr, b1p, W1h, W1l,
                                               nbrT, sA, sB, sC, ssp);
    // mlp computes g AND performs walk step 1 (scatter into sA)
    mlp_mfma_kernel<<<(NN + 63) / 64, 256, 0, stream>>>(emb, W1h, W1l, b1p, W2, b2,
                                                        nbrT, gbuf, sA);

    walk_step_kernel<<<nblk, 256, 0, stream>>>(gbuf, nbrT, sA, sB);
    walk_step_kernel<<<nblk, 256, 0, stream>>>(gbuf, nbrT, sB, sC);

    norm_reduce_kernel<<<512, 256, 0, stream>>>(sC, ssp);
    finalize_kernel<<<nblk, 256, 0, stream>>>(sC, ssp, out);
}